// Round 8
// baseline (343.785 us; speedup 1.0000x reference)
//
#include <hip/hip_runtime.h>
#include <hip/hip_bf16.h>
#include <cstddef>

#define EE 1024            // E
#define MTOT 8192          // B*E

using floatx4 = __attribute__((ext_vector_type(4))) float;
using bf16x8  = __attribute__((ext_vector_type(8))) __bf16;

union FragU { uint4 u; bf16x8 b; };

__device__ __forceinline__ float elu1(float x) {
    return x > 0.f ? x + 1.f : __expf(x);
}

__device__ __forceinline__ unsigned int pack2bf(float x, float y) {
    __hip_bfloat162 h = __float22bfloat162_rn(make_float2(x, y));
    union { __hip_bfloat162 h; unsigned int u; } c;
    c.h = h;
    return c.u;
}

__device__ __forceinline__ uint4 pack8bf(const float4 a, const float4 b) {
    uint4 r;
    r.x = pack2bf(a.x, a.y); r.y = pack2bf(a.z, a.w);
    r.z = pack2bf(b.x, b.y); r.w = pack2bf(b.z, b.w);
    return r;
}

__device__ __forceinline__ unsigned short f2bf(float x) {
    union { __hip_bfloat16 h; unsigned short s; } c;
    c.h = __float2bfloat16(x);
    return c.s;
}

__device__ __forceinline__ void unp8(const uint4 p, float4& a, float4& b) {
    a.x = __uint_as_float(p.x << 16); a.y = __uint_as_float(p.x & 0xffff0000u);
    a.z = __uint_as_float(p.y << 16); a.w = __uint_as_float(p.y & 0xffff0000u);
    b.x = __uint_as_float(p.z << 16); b.y = __uint_as_float(p.z & 0xffff0000u);
    b.z = __uint_as_float(p.w << 16); b.w = __uint_as_float(p.w & 0xffff0000u);
}

__device__ __forceinline__ void ld_lds16(const unsigned short* g, unsigned short* l) {
    __builtin_amdgcn_global_load_lds(
        (const __attribute__((address_space(1))) void*)g,
        (__attribute__((address_space(3))) void*)l, 16, 0, 0);
}

// Fused fp32 -> bf16 bulk convert: x | Wq | Wk | Wv | Wo in one launch.
__global__ __launch_bounds__(256)
void cvt_all(const float* __restrict__ x,
             const float* __restrict__ Wq, const float* __restrict__ Wk,
             const float* __restrict__ Wv, const float* __restrict__ Wo,
             unsigned short* __restrict__ xb,
             unsigned short* __restrict__ wb, unsigned short* __restrict__ wob) {
    const int i = blockIdx.x * 256 + threadIdx.x;
    if (i >= 3014656) return;
    const float* src;
    unsigned short* dst;
    int off;
    if (i < 2097152)      { src = x;  dst = xb;           off = i; }
    else if (i < 2359296) { src = Wq; dst = wb;           off = i - 2097152; }
    else if (i < 2621440) { src = Wk; dst = wb + 2097152; off = i - 2359296; }
    else if (i < 2883584) { src = Wv; dst = wb + 4194304; off = i - 2621440; }
    else                  { src = Wo; dst = wob;          off = i - 2883584; }
    const float4 a = ((const float4*)src)[2 * off];
    const float4 b = ((const float4*)src)[2 * off + 1];
    ((uint4*)dst)[off] = pack8bf(a, b);
}

// ============================================================================
// 256x256 8-phase counted-vmcnt QKV GEMM (m201-style schedule, r7-proven LDS
// addressing). A=xb [8192][2048], B=wb [3072][2048] (B^T layout). 8 waves
// (2M x 4N), per-wave 128x64 out, BK=64, 2 K-tiles/iter, 128 KiB LDS dbuf.
//
// LDS: plain row-major [256][64] ushort per tile. Chunk c (16B) of row r is
// stored at position (c + r) & 7 -- achieved by global_load_lds with LINEAR
// wave-uniform dest (8 rows/instr: lane l -> row l>>3, pos l&7) and the
// rotation applied on the per-lane global SOURCE chunk sc = ((l&7)-(l>>3))&7.
// Coalescing preserved (permutation within each 128B row); frag ds_read
// position (quad+lm)&7 / ^4 -> 8 distinct 16B bank-slots per octet -> ZERO
// conflicts. [All three properties HW-verified in rounds 6-7.]
//
// Phase schedule per iter (tiles t->b0, t+1->b1), stage regions only ever
// overwrite rows whose fragments were register-captured >=1 barrier earlier:
//  ph1 c(b0,MH0,NH0) rd A-MH0,B-all(b0) | st B-SH1(t+1->b1)
//  ph2 c(b0,MH0,NH1)                    | st A-SH1(t+1->b1)
//  ph3 c(b0,MH1,NH0) rd A-MH1(b0)       | st A-SH0(t+2->b0)   [A-SH0 dead: rd ph1]
//  ph4 c(b0,MH1,NH1)                    | st B-SH0(t+2->b0), vmcnt(4) -> t+1 ready
//  ph5 c(b1,MH0,NH0) rd A-MH0,B-all(b1) | st B-SH1(t+2->b0)   [B b0 dead: rd ph1]
//  ph6 c(b1,MH0,NH1)                    | st A-SH1(t+2->b0)   [dead: rd ph3]
//  ph7 c(b1,MH1,NH0) rd A-MH1(b1)       | st A-SH0(t+3->b1)
//  ph8 c(b1,MH1,NH1)                    | st B-SH0(t+3->b1), vmcnt(4) -> t+2 ready
// vmcnt(4): 12 outstanding, waits all but newest 4 (FIFO) = exactly the next
// tile's 8 + carry. B-frags held in regs across ph1-ph4 (24 ds_read/K-tile =
// 0.375/MFMA). Final vmcnt(0) drains clamped refetches before endpgm.
// ============================================================================

#define BARX()  __builtin_amdgcn_s_barrier()
#define LGK0()  asm volatile("s_waitcnt lgkmcnt(0)" ::: "memory")
#define SCB0()  __builtin_amdgcn_sched_barrier(0)

#define SAG(G, KT, DST) do { \
    const unsigned short* s_ = Ab + (size_t)(m0 + 8 * (G) + lr) * 2048 + (size_t)(KT) * 64 + sc * 8; \
    ld_lds16(s_, &DST[(8 * (G)) * 64]); \
} while (0)

#define SBG(G, KT, DST) do { \
    const unsigned short* s_ = Bb + (size_t)(n0 + 8 * (G) + lr) * 2048 + (size_t)(KT) * 64 + sc * 8; \
    ld_lds16(s_, &DST[(8 * (G)) * 64]); \
} while (0)

#define RDA(SRC, MH) do { \
    _Pragma("unroll") \
    for (int i2 = 0; i2 < 4; ++i2) { \
        const int r_ = (wr * 128 + ((MH) * 4 + i2) * 16 + lm) * 64; \
        A8[i2][0].u = *(const uint4*)&SRC[r_ + p0]; \
        A8[i2][1].u = *(const uint4*)&SRC[r_ + p1]; \
    } \
} while (0)

#define RDB(SRC) do { \
    _Pragma("unroll") \
    for (int j_ = 0; j_ < 4; ++j_) { \
        const int r_ = (wc * 64 + j_ * 16 + lm) * 64; \
        B8[j_][0].u = *(const uint4*)&SRC[r_ + p0]; \
        B8[j_][1].u = *(const uint4*)&SRC[r_ + p1]; \
    } \
} while (0)

#define MMQ(MH, NH) do { \
    __builtin_amdgcn_s_setprio(1); \
    _Pragma("unroll") \
    for (int i2 = 0; i2 < 4; ++i2) \
        _Pragma("unroll") \
        for (int j2 = 0; j2 < 2; ++j2) { \
            acc[(MH) * 4 + i2][(NH) * 2 + j2] = __builtin_amdgcn_mfma_f32_16x16x32_bf16( \
                A8[i2][0].b, B8[(NH) * 2 + j2][0].b, acc[(MH) * 4 + i2][(NH) * 2 + j2], 0, 0, 0); \
            acc[(MH) * 4 + i2][(NH) * 2 + j2] = __builtin_amdgcn_mfma_f32_16x16x32_bf16( \
                A8[i2][1].b, B8[(NH) * 2 + j2][1].b, acc[(MH) * 4 + i2][(NH) * 2 + j2], 0, 0, 0); \
        } \
    __builtin_amdgcn_s_setprio(0); \
} while (0)

__global__ __launch_bounds__(512, 2)
void gemm_qkv256(const unsigned short* __restrict__ Ab, const unsigned short* __restrict__ Bb,
                 const float* __restrict__ bq, const float* __restrict__ bk,
                 const float* __restrict__ bv,
                 unsigned short* __restrict__ qo, unsigned short* __restrict__ ko,
                 unsigned short* __restrict__ vo) {
    __shared__ __align__(16) unsigned short sA_0[16384], sA_1[16384];
    __shared__ __align__(16) unsigned short sB_0[16384], sB_1[16384];

    // bijective XCD swizzle: 384 blocks = 8 XCDs x 48
    int id = blockIdx.y * 12 + blockIdx.x;
    id = (id & 7) * 48 + (id >> 3);
    const int m0 = (id / 12) * 256;
    const int n0 = (id % 12) * 256;

    const int t = threadIdx.x;
    const int w = t >> 6, l = t & 63;
    const int lm = l & 15, quad = l >> 4;
    const int wr = w >> 2, wc = w & 3;
    const int lr = l >> 3;
    const int sc = ((l & 7) - lr) & 7;              // pre-swizzled source chunk
    const int p0 = ((quad + lm) & 7) * 8;           // frag read positions
    const int p1 = (((quad + lm) & 7) ^ 4) * 8;

    // per-wave stage granules (8 rows each; SH-regions align with read phases)
    const int ga0a = w,               ga0b = w + 16;      // A-SH0 (MH0 rows)
    const int ga1a = w + 8,           ga1b = w + 24;      // A-SH1 (MH1 rows)
    const int gb0a = (w & 3) + 8 * (w >> 2), gb0b = gb0a + 16;  // B-SH0 (NH0)
    const int gb1a = gb0a + 4,        gb1b = gb0a + 20;         // B-SH1 (NH1)

    floatx4 acc[8][4];
    #pragma unroll
    for (int i = 0; i < 8; ++i)
        #pragma unroll
        for (int j = 0; j < 4; ++j)
            acc[i][j] = (floatx4)(0.f);
    FragU A8[4][2], B8[4][2];

    // prologue: tile0 full -> b0 (8 instr), tile1 SH0s -> b1 (4 instr)
    SAG(ga0a, 0, sA_0); SAG(ga0b, 0, sA_0);
    SAG(ga1a, 0, sA_0); SAG(ga1b, 0, sA_0);
    SBG(gb0a, 0, sB_0); SBG(gb0b, 0, sB_0);
    SBG(gb1a, 0, sB_0); SBG(gb1b, 0, sB_0);
    SAG(ga0a, 1, sA_1); SAG(ga0b, 1, sA_1);
    SBG(gb0a, 1, sB_1); SBG(gb0b, 1, sB_1);
    asm volatile("s_waitcnt vmcnt(4)" ::: "memory");   // tile0's 8 done
    BARX();

    #pragma unroll 1
    for (int s = 0; s < 32; s += 2) {
        const int k1 = s + 1;
        const int k2 = (s + 2 < 32) ? s + 2 : 31;   // clamped refetch (never read)
        const int k3 = (s + 3 < 32) ? s + 3 : 31;
        // ph1
        RDA(sA_0, 0); RDB(sB_0);
        SBG(gb1a, k1, sB_1); SBG(gb1b, k1, sB_1);
        BARX(); LGK0(); SCB0(); MMQ(0, 0); BARX();
        // ph2
        SAG(ga1a, k1, sA_1); SAG(ga1b, k1, sA_1);
        BARX(); MMQ(0, 1); BARX();
        // ph3
        RDA(sA_0, 1);
        SAG(ga0a, k2, sA_0); SAG(ga0b, k2, sA_0);
        BARX(); LGK0(); SCB0(); MMQ(1, 0); BARX();
        // ph4
        SBG(gb0a, k2, sB_0); SBG(gb0b, k2, sB_0);
        asm volatile("s_waitcnt vmcnt(4)" ::: "memory");
        BARX(); MMQ(1, 1); BARX();
        // ph5
        RDA(sA_1, 0); RDB(sB_1);
        SBG(gb1a, k2, sB_0); SBG(gb1b, k2, sB_0);
        BARX(); LGK0(); SCB0(); MMQ(0, 0); BARX();
        // ph6
        SAG(ga1a, k2, sA_0); SAG(ga1b, k2, sA_0);
        BARX(); MMQ(0, 1); BARX();
        // ph7
        RDA(sA_1, 1);
        SAG(ga0a, k3, sA_1); SAG(ga0b, k3, sA_1);
        BARX(); LGK0(); SCB0(); MMQ(1, 0); BARX();
        // ph8
        SBG(gb0a, k3, sB_1); SBG(gb0b, k3, sB_1);
        asm volatile("s_waitcnt vmcnt(4)" ::: "memory");
        BARX(); MMQ(1, 1); BARX();
    }
    // drain clamped refetches before epilogue/endpgm
    asm volatile("s_waitcnt vmcnt(0)" ::: "memory");
    BARX();

    // epilogue (mapping numerically verified in round 2's variant)
    const int proj = n0 >> 10;
    unsigned short* Cb = proj == 0 ? qo : (proj == 1 ? ko : vo);
    const float* bias  = proj == 0 ? bq : (proj == 1 ? bk : bv);
    const int ndb = (n0 & 1023) + wc * 64;
    #pragma unroll
    for (int j = 0; j < 4; ++j) {
        const int d = ndb + j * 16 + lm;
        const float bj = bias[d];
        #pragma unroll
        for (int i = 0; i < 8; ++i) {
            const int row0 = m0 + wr * 128 + i * 16 + quad * 4;
            #pragma unroll
            for (int r = 0; r < 4; ++r)
                Cb[(size_t)(row0 + r) * 1024 + d] = f2bf(acc[i][j][r] + bj);
        }
    }
}

// ---- m97-style MFMA core, BK=64 (r7-proven; kept for gemm_out).
template<int K>
__device__ __forceinline__ void mfma_core(const unsigned short* __restrict__ A,
                                          const unsigned short* __restrict__ B,
                                          int m0, int n0,
                                          unsigned short* As, unsigned short* Bs,
                                          floatx4 (&acc)[4][4]) {
    const int t = threadIdx.x;
    const int w = t >> 6, l = t & 63;
    const int wm = (w >> 1) * 64, wn = (w & 1) * 64;
    const int lm = l & 15, lq = l >> 4;
    const int lr = l >> 3;
    const int sc = ((l & 7) - lr) & 7;
    const int c0 = (lq + lm) & 7;

    const unsigned short* Ag = A + (size_t)(m0 + 32 * w + lr) * K + sc * 8;
    const unsigned short* Bg = B + (size_t)(n0 + 32 * w + lr) * K + sc * 8;
    unsigned short* Al = As + (32 * w) * 64;
    unsigned short* Bl = Bs + (32 * w) * 64;

    for (int kb = 0; kb < K; kb += 64) {
        __syncthreads();
        #pragma unroll
        for (int p = 0; p < 4; ++p) {
            ld_lds16(Ag + (size_t)(8 * p) * K + kb, Al + (8 * p) * 64);
            ld_lds16(Bg + (size_t)(8 * p) * K + kb, Bl + (8 * p) * 64);
        }
        __syncthreads();
        FragU af[4][2], bf[4][2];
        #pragma unroll
        for (int i = 0; i < 4; ++i) {
            const int row = (wm + i * 16 + lm) * 64;
            af[i][0].u = *(const uint4*)&As[row + c0 * 8];
            af[i][1].u = *(const uint4*)&As[row + (c0 ^ 4) * 8];
        }
        #pragma unroll
        for (int j = 0; j < 4; ++j) {
            const int row = (wn + j * 16 + lm) * 64;
            bf[j][0].u = *(const uint4*)&Bs[row + c0 * 8];
            bf[j][1].u = *(const uint4*)&Bs[row + (c0 ^ 4) * 8];
        }
        #pragma unroll
        for (int i = 0; i < 4; ++i)
            #pragma unroll
            for (int j = 0; j < 4; ++j) {
                acc[i][j] = __builtin_amdgcn_mfma_f32_16x16x32_bf16(
                    af[i][0].b, bf[j][0].b, acc[i][j], 0, 0, 0);
                acc[i][j] = __builtin_amdgcn_mfma_f32_16x16x32_bf16(
                    af[i][1].b, bf[j][1].b, acc[i][j], 0, 0, 0);
            }
    }
}

// Output projection: A=attn bf16 [8192][1024], B=wob [1024][1024]. fp32 out.
__global__ __launch_bounds__(256)
void gemm_out(const unsigned short* __restrict__ A, const unsigned short* __restrict__ B,
              const float* __restrict__ bo, float* __restrict__ C) {
    __shared__ __align__(16) unsigned short As[128 * 64];
    __shared__ __align__(16) unsigned short Bs[128 * 64];
    const int m0 = blockIdx.y * 128;
    const int n0 = blockIdx.x * 128;
    floatx4 acc[4][4];
    #pragma unroll
    for (int i = 0; i < 4; ++i)
        #pragma unroll
        for (int j = 0; j < 4; ++j)
            acc[i][j] = (floatx4)(0.f);
    mfma_core<1024>(A, B, m0, n0, As, Bs, acc);

    const int t = threadIdx.x;
    const int w = t >> 6, l = t & 63;
    const int wm = (w >> 1) * 64, wn = (w & 1) * 64;
    const int lm = l & 15, lq = l >> 4;
    #pragma unroll
    for (int j = 0; j < 4; ++j) {
        const int col = n0 + wn + j * 16 + lm;
        const float bj = bo[col];
        #pragma unroll
        for (int i = 0; i < 4; ++i) {
            #pragma unroll
            for (int r = 0; r < 4; ++r) {
                const int row = m0 + wm + i * 16 + lq * 4 + r;
                C[(size_t)row * EE + col] = acc[i][j][r] + bj;
            }
        }
    }
}

// ---- Stage 1 (MFMA): Sk[d][e] = sum_s sigma_k[s][d]*v[s][e], z[d]=colsum(sigma_k).
__global__ __launch_bounds__(256)
void seg_kv(const unsigned short* __restrict__ k, const unsigned short* __restrict__ v,
            float* __restrict__ Skv, float* __restrict__ zc) {
    __shared__ __align__(16) unsigned short KT[64 * 72];  // sigma_k^T [d][s]
    __shared__ __align__(16) unsigned short VT[64 * 72];  // v^T       [e][s]
    const int t = threadIdx.x;
    const int w = t >> 6, l = t & 63, quad = l >> 4, lm = l & 15;
    const size_t base = (size_t)blockIdx.x * 4096;

    #pragma unroll
    for (int i = 0; i < 2; ++i) {
        const int c  = t + i * 256;            // uint4 chunk
        const int sr = c >> 3, c0 = (c & 7) * 8;
        const uint4 pk = *(const uint4*)(k + base + c * 8);
        const uint4 pv = *(const uint4*)(v + base + c * 8);
        float4 f0, f1;
        unp8(pk, f0, f1);
        KT[(c0 + 0) * 72 + sr] = f2bf(elu1(f0.x));
        KT[(c0 + 1) * 72 + sr] = f2bf(elu1(f0.y));
        KT[(c0 + 2) * 72 + sr] = f2bf(elu1(f0.z));
        KT[(c0 + 3) * 72 + sr] = f2bf(elu1(f0.w));
        KT[(c0 + 4) * 72 + sr] = f2bf(elu1(f1.x));
        KT[(c0 + 5) * 72 + sr] = f2bf(elu1(f1.y));
        KT[(c0 + 6) * 72 + sr] = f2bf(elu1(f1.z));
        KT[(c0 + 7) * 72 + sr] = f2bf(elu1(f1.w));
        const unsigned short* pvs = (const unsigned short*)&pv;
        #pragma unroll
        for (int jj = 0; jj < 8; ++jj) VT[(c0 + jj) * 72 + sr] = pvs[jj];
    }
    __syncthreads();

    if (t < 64) {                                  // z[d] = rowsum of KT row d
        float ssum = 0.f;
        #pragma unroll
        for (int c2 = 0; c2 < 8; ++c2) {
            const uint4 p = *(const uint4*)&KT[t * 72 + c2 * 8];
            float4 a, b;
            unp8(p, a, b);
            ssum += a.x + a.y + a.z + a.w + b.x + b.y + b.z + b.w;
        }
        zc[(size_t)blockIdx.x * 64 + t] = ssum;
    }

    FragU ak0, ak1;
    ak0.u = *(const uint4*)&KT[(16 * w + lm) * 72 + quad * 8];
    ak1.u = *(const uint4*)&KT[(16 * w + lm) * 72 + 32 + quad * 8];
    floatx4 C4[4];
    #pragma unroll
    for (int j = 0; j < 4; ++j) C4[j] = (floatx4)(0.f);
    #pragma unroll
    for (int j = 0; j < 4; ++j) {
        FragU b0, b1;
        b0.u = *(const uint4*)&VT[(j * 16 + lm) * 72 + quad * 8];
        b1.u = *(const uint4*)&VT[(j * 16 + lm) * 72 + 32 + quad * 8];
        C4[j] = __builtin_amdgcn_mfma_f32_16x16x32_bf16(ak0.b, b0.b, C4[j], 0, 0, 0);
        C4[j] = __builtin_amdgcn_mfma_f32_16x16x32_bf16(ak1.b, b1.b, C4[j], 0, 0, 0);
    }
    const int d0 = 16 * w + quad * 4;
    #pragma unroll
    for (int j = 0; j < 4; ++j)
        #pragma unroll
        for (int r = 0; r < 4; ++r)
            Skv[base + (size_t)(d0 + r) * 64 + j * 16 + lm] = C4[j][r];
}

// ---- Stage 2: exclusive prefix over 16 segments per (b,h) chain.
// fp32 accumulation (numerics unchanged); OUTPUT is bf16 [seg][d][e] only
// (seg_attn converted to bf16 anyway -> identical downstream numerics).
__global__ __launch_bounds__(256)
void prefix_mem(const float* __restrict__ Skv, unsigned short* __restrict__ Skvb,
                float* __restrict__ zc) {
    const int t  = threadIdx.x;
    const int bh = blockIdx.y;
    const size_t off = (size_t)bh * 16 * 4096 + blockIdx.x * 512 + t * 2;
    float2 acc = make_float2(0.f, 0.f);
    #pragma unroll
    for (int n = 0; n < 16; ++n) {
        const float2 tmp = *(const float2*)(Skv + off + (size_t)n * 4096);
        *(unsigned int*)(Skvb + off + (size_t)n * 4096) = pack2bf(acc.x, acc.y);
        acc.x += tmp.x; acc.y += tmp.y;
    }
    if (blockIdx.x == 0 && t < 64) {
        float* zp0 = zc + (size_t)bh * 16 * 64 + t;
        float za = 0.f;
        #pragma unroll
        for (int n = 0; n < 16; ++n) {
            float* zp = zp0 + n * 64;
            const float tmp = *zp;
            *zp = za;
            za += tmp;
        }
    }
}

// ---- Stage 3 (MFMA): per-segment attention. mem now bf16 [d][e].
__global__ __launch_bounds__(256)
void seg_attn(const unsigned short* __restrict__ q, const unsigned short* __restrict__ k,
              const unsigned short* __restrict__ v, const unsigned short* __restrict__ memb,
              const float* __restrict__ zp, const float* __restrict__ beta,
              unsigned short* __restrict__ ab) {
    __shared__ __align__(16) unsigned short Pb[64 * 72];  // P bf16 [s][t]
    __shared__ __align__(16) unsigned short VT[64 * 72];  // v^T    [e][s]
    __shared__ __align__(16) unsigned short MT[64 * 72];  // mem^T  [e][d]
    __shared__ float rs[64];
    __shared__ float zr[64];
    const int t = threadIdx.x;
    const int w = t >> 6, l = t & 63, quad = l >> 4, lm = l & 15;
    const int seg = blockIdx.x;
    const int h   = (seg >> 4) & 15;
    const float gate = 1.f / (1.f + __expf(-10.f * beta[h]));
    const float omg  = 1.f - gate;
    const size_t base = (size_t)seg * 4096;

    // stage v^T
    #pragma unroll
    for (int i = 0; i < 2; ++i) {
        const int c  = t + i * 256;
        const int sr = c >> 3, c0 = (c & 7) * 8;
        const uint4 pv = *(const uint4*)(v + base + c * 8);
        const unsigned short* pvs = (const unsigned short*)&pv;
        #pragma unroll
        for (int jj = 0; jj < 8; ++jj) VT[(c0 + jj) * 72 + sr] = pvs[jj];
    }
    // stage mem^T (bf16 copy; source [d][e])
    #pragma unroll
    for (int i = 0; i < 2; ++i) {
        const int c = t + i * 256;
        const int d = c >> 3, e0 = (c & 7) * 8;
        const uint4 pm = *(const uint4*)(memb + base + c * 8);
        const unsigned short* pms = (const unsigned short*)&pm;
        #pragma unroll
        for (int jj = 0; jj < 8; ++jj) MT[(e0 + jj) * 72 + d] = pms[jj];
    }
    // rs[s] = rowsum(sigma_q): quarter-row per thread + shfl reduce
    {
        const int s = t >> 2, dq = (t & 3) * 16;
        const uint4 a0 = *(const uint4*)(q + base + s * 64 + dq);
        const uint4 a1 = *(const uint4*)(q + base + s * 64 + dq + 8);
        float4 f0, f1, f2, f3;
        unp8(a0, f0, f1); unp8(a1, f2, f3);
        float p = elu1(f0.x) + elu1(f0.y) + elu1(f0.z) + elu1(f0.w)
                + elu1(f1.x) + elu1(f1.y) + elu1(f1.z) + elu1(f1.w)
                + elu1(f2.x) + elu1(f2.y) + elu1(f2.z) + elu1(f2.w)
                + elu1(f3.x) + elu1(f3.y) + elu1(f3.z) + elu1(f3.w);
        p += __shfl_xor(p, 1, 64);
        p += __shfl_xor(p, 2, 64);
        if ((t & 3) == 0) rs[s] = p;
    }
    if (t < 64) zr[t] = zp[(size_t)seg * 64 + t];
    __syncthreads();

    // ---- scores: wave w computes rows [16w,16w+16) x all 64 cols
    const unsigned short* qrow = q + base + (size_t)(16 * w + lm) * 64;
    FragU aq0, aq1;
    aq0.u = *(const uint4*)(qrow + quad * 8);
    aq1.u = *(const uint4*)(qrow + 32 + quad * 8);
    floatx4 S[4];
    #pragma unroll
    for (int j = 0; j < 4; ++j) S[j] = (floatx4)(0.f);
    #pragma unroll
    for (int j = 0; j < 4; ++j) {
        const unsigned short* krow = k + base + (size_t)(j * 16 + lm) * 64;
        FragU b0, b1;
        b0.u = *(const uint4*)(krow + quad * 8);
        b1.u = *(const uint4*)(krow + 32 + quad * 8);
        S[j] = __builtin_amdgcn_mfma_f32_16x16x32_bf16(aq0.b, b0.b, S[j], 0, 0, 0);
        S[j] = __builtin_amdgcn_mfma_f32_16x16x32_bf16(aq1.b, b1.b, S[j], 0, 0, 0);
    }
    // ---- causal softmax in C-layout registers; write P bf16 to LDS
    const int srow0 = 16 * w + quad * 4;
    #pragma unroll
    for (int r = 0; r < 4; ++r) {
        const int s_g = srow0 + r;
        float m = -3.0e38f;
        #pragma unroll
        for (int j = 0; j < 4; ++j) {
            const int t_g = j * 16 + lm;
            const float val = (t_g <= s_g) ? S[j][r] * 0.125f : -3.0e38f;
            S[j][r] = val;
            m = fmaxf(m, val);
        }
        m = fmaxf(m, __shfl_xor(m, 1, 64));
        m = fmaxf(m, __shfl_xor(m, 2, 64));
        m = fmaxf(m, __shfl_xor(m, 4, 64));
        m = fmaxf(m, __shfl_xor(m, 8, 64));
        float ss = 0.f;
        #pragma unroll
        for (int j = 0; j < 4; ++j) {
            const int t_g = j * 16 + lm;
            const float e = (t_g <= s_g) ? __expf(S[j][r] - m) : 0.f;
            S[j][r] = e;
            ss += e;
        }
        ss += __shfl_xor(ss, 1, 64);
        ss += __shfl_xor(ss, 2, 64);
        ss += __shfl_xor(ss, 4, 64);
        ss += __shfl_xor(ss, 8, 64);
        const float inv = 1.f / ss;
        #pragma unroll
        for (int j = 0; j < 4; ++j)
            Pb[s_g * 72 + j * 16 + lm] = f2bf(S[j][r] * inv);
    }
    __syncthreads();

    // ---- A_dot = P@V and A_mem = sigma_q@mem (both C-layout accumulators)
    FragU ap0, ap1, as0, as1;
    ap0.u = *(const uint4*)&Pb[(16 * w + lm) * 72 + quad * 8];
    ap1.u = *(const uint4*)&Pb[(16 * w + lm) * 72 + 32 + quad * 8];
    {
        float4 f0, f1, f2, f3;
        unp8(aq0.u, f0, f1);
        unp8(aq1.u, f2, f3);
        f0.x = elu1(f0.x); f0.y = elu1(f0.y); f0.z = elu1(f0.z); f0.w = elu1(f0.w);
        f1.x = elu1(f1.x); f1.y = elu1(f1.y); f1.z = elu1(f1.z); f1.w = elu1(f1.w);
        f2.x = elu1(f2.x); f2.y = elu1(f2.y); f2.z = elu1(f2.z); f2.w = elu1(f2.w);
        f3.x = elu1(f3.x); f3.y = elu1(f3.y); f3.z = elu1(f3.z); f3.w = elu1(f3.w);
        as0.u = pack8bf(f0, f1);
        as1.u = pack8bf(f2, f3);
    }
    floatx4 AD[4], AM[4];
    #pragma unroll
    for (int j = 0; j < 4; ++j) { AD[j] = (floatx4)(0.f); AM[j] = (floatx4)(0.f); }
    #pragma unroll
    for (int j = 0; j < 4; ++j) {
        FragU bv0, bv1, bm0, bm1;
        bv0.u = *(const uint4*)&VT[(j * 16 + lm) * 72 + quad * 8];
        bv1.u = *(const uint4*)&VT[(j * 16 + lm) * 72 + 32 + quad * 8];
        bm0.u = *(const uint4*)&MT[(j * 16 + lm) * 72 + quad * 8];
        bm1.u = *(const uint4*)&MT[(j * 16 + lm) * 72 + 32 + quad * 8];
        AD[j] = __builtin_amdgcn_mfma_f32_16x16x32_bf16(ap0.b, bv0.b, AD[j], 0, 0, 0);
        AD[j] = __builtin_amdgcn_mfma_f32_16x16x32_bf16(ap1.b, bv1.b, AD[j], 0, 0, 0);
        AM[j] = __builtin_amdgcn_mfma_f32_16x16x32_bf16(as0.b, bm0.b, AM[j], 0, 0, 0);
        AM[j] = __builtin_amdgcn_mfma_f32_16x16x32_bf16(as1.b, bm1.b, AM[j], 0, 0, 0);
    }
    // ---- combine + store attn bf16
    #pragma unroll
    for (int j = 0; j < 4; ++j) {
        const int d = j * 16 + lm;
        const float zd = zr[d];
        #pragma unroll
        for (int r = 0; r < 4; ++r) {
            const int s_g = srow0 + r;
            const float den = rs[s_g] * zd + 1e-6f;
            const float o = gate * (AM[j][r] / den) + omg * AD[j][r];
            ab[base + (size_t)s_g * 64 + d] = f2bf(o);
        }
    }
}

extern "C" void kernel_launch(void* const* d_in, const int* in_sizes, int n_in,
                              void* d_out, int out_size, void* d_ws, size_t ws_size,
                              hipStream_t stream) {
    const float* x    = (const float*)d_in[0];
    const float* Wq   = (const float*)d_in[1];
    const float* bq   = (const float*)d_in[2];
    const float* Wk   = (const float*)d_in[3];
    const float* bk   = (const float*)d_in[4];
    const float* Wv   = (const float*)d_in[5];
    const float* bv   = (const float*)d_in[6];
    const float* Wo   = (const float*)d_in[7];
    const float* bo   = (const float*)d_in[8];
    const float* beta = (const float*)d_in[9];
    float* out = (float*)d_out;

    unsigned char* wsb = (unsigned char*)d_ws;
    unsigned short* xb  = (unsigned short*)(wsb);                       // 32 MB
    unsigned short* wb  = (unsigned short*)(wsb + (32ull << 20));       // 12 MB  [3072][2048]
    unsigned short* wob = (unsigned short*)(wsb + (44ull << 20));       // 2 MB   [1024][1024]
    unsigned short* qb  = (unsigned short*)(wsb + (46ull << 20));       // 16 MB
    unsigned short* kb  = (unsigned short*)(wsb + (62ull << 20));       // 16 MB
    unsigned short* vb  = (unsigned short*)(wsb + (78ull << 20));       // 16 MB
    float* Skv = (float*)(wsb + (94ull << 20));                         // 32 MB
    float* zc  = (float*)(wsb + (126ull << 20));                        // 0.5 MB
    unsigned short* ab   = xb;                                          // first 16 MB of xb (dead after gemm_qkv)
    unsigned short* Skvb = (unsigned short*)(wsb + (16ull << 20));      // second 16 MB of xb (dead after gemm_qkv)

    cvt_all<<<11776, 256, 0, stream>>>(x, Wq, Wk, Wv, Wo, xb, wb, wob);

    gemm_qkv256<<<dim3(12, 32), 512, 0, stream>>>(xb, wb, bq, bk, bv, qb, kb, vb);
    seg_kv<<<2048, 256, 0, stream>>>(kb, vb, Skv, zc);
    prefix_mem<<<dim3(8, 128), 256, 0, stream>>>(Skv, Skvb, zc);
    seg_attn<<<2048, 256, 0, stream>>>(qb, kb, vb, Skvb, zc, beta, ab);
    gemm_out<<<dim3(8, 64), 256, 0, stream>>>(ab, wob, bo, out);
}

// Round 9
// 319.484 us; speedup vs baseline: 1.0761x; 1.0761x over previous
//
#include <hip/hip_runtime.h>
#include <hip/hip_bf16.h>
#include <cstddef>

#define EE 1024            // E
#define MTOT 8192          // B*E

using floatx4 = __attribute__((ext_vector_type(4))) float;
using bf16x8  = __attribute__((ext_vector_type(8))) __bf16;

union FragU { uint4 u; bf16x8 b; };

__device__ __forceinline__ float elu1(float x) {
    return x > 0.f ? x + 1.f : __expf(x);
}

__device__ __forceinline__ unsigned int pack2bf(float x, float y) {
    __hip_bfloat162 h = __float22bfloat162_rn(make_float2(x, y));
    union { __hip_bfloat162 h; unsigned int u; } c;
    c.h = h;
    return c.u;
}

__device__ __forceinline__ uint4 pack8bf(const float4 a, const float4 b) {
    uint4 r;
    r.x = pack2bf(a.x, a.y); r.y = pack2bf(a.z, a.w);
    r.z = pack2bf(b.x, b.y); r.w = pack2bf(b.z, b.w);
    return r;
}

__device__ __forceinline__ unsigned short f2bf(float x) {
    union { __hip_bfloat16 h; unsigned short s; } c;
    c.h = __float2bfloat16(x);
    return c.s;
}

__device__ __forceinline__ void unp8(const uint4 p, float4& a, float4& b) {
    a.x = __uint_as_float(p.x << 16); a.y = __uint_as_float(p.x & 0xffff0000u);
    a.z = __uint_as_float(p.y << 16); a.w = __uint_as_float(p.y & 0xffff0000u);
    b.x = __uint_as_float(p.z << 16); b.y = __uint_as_float(p.z & 0xffff0000u);
    b.z = __uint_as_float(p.w << 16); b.w = __uint_as_float(p.w & 0xffff0000u);
}

__device__ __forceinline__ void ld_lds16(const unsigned short* g, unsigned short* l) {
    __builtin_amdgcn_global_load_lds(
        (const __attribute__((address_space(1))) void*)g,
        (__attribute__((address_space(3))) void*)l, 16, 0, 0);
}

// Fused fp32 -> bf16 bulk convert: x | Wq | Wk | Wv | Wo in one launch.
__global__ __launch_bounds__(256)
void cvt_all(const float* __restrict__ x,
             const float* __restrict__ Wq, const float* __restrict__ Wk,
             const float* __restrict__ Wv, const float* __restrict__ Wo,
             unsigned short* __restrict__ xb,
             unsigned short* __restrict__ wb, unsigned short* __restrict__ wob) {
    const int i = blockIdx.x * 256 + threadIdx.x;
    if (i >= 3014656) return;
    const float* src;
    unsigned short* dst;
    int off;
    if (i < 2097152)      { src = x;  dst = xb;           off = i; }
    else if (i < 2359296) { src = Wq; dst = wb;           off = i - 2097152; }
    else if (i < 2621440) { src = Wk; dst = wb + 2097152; off = i - 2359296; }
    else if (i < 2883584) { src = Wv; dst = wb + 4194304; off = i - 2621440; }
    else                  { src = Wo; dst = wob;          off = i - 2883584; }
    const float4 a = ((const float4*)src)[2 * off];
    const float4 b = ((const float4*)src)[2 * off + 1];
    ((uint4*)dst)[off] = pack8bf(a, b);
}

// ---- m97-style MFMA core, BK=64 (r7-proven: 868 TF, 0 bank conflicts):
// bf16 A[M][K] x B[N][K]^T, 128x128 tile, global_load_lds width-16 staging,
// LDS [128][64] ushort (128B rows), 32 KiB total.
// Chunk swizzle: chunk c of row r stored at (c + r) & 7; staging applies the
// inverse rotation on the global SOURCE chunk (within each 128B row ->
// coalescing preserved); frag reads at ((lq+lm)&7) / ^4 -> zero conflicts.
template<int K>
__device__ __forceinline__ void mfma_core(const unsigned short* __restrict__ A,
                                          const unsigned short* __restrict__ B,
                                          int m0, int n0,
                                          unsigned short* As, unsigned short* Bs,
                                          floatx4 (&acc)[4][4]) {
    const int t = threadIdx.x;
    const int w = t >> 6, l = t & 63;
    const int wm = (w >> 1) * 64, wn = (w & 1) * 64;
    const int lm = l & 15, lq = l >> 4;
    const int lr = l >> 3;                       // row within 8-row stage group
    const int sc = ((l & 7) - lr) & 7;           // pre-swizzled source chunk
    const int c0 = (lq + lm) & 7;                // read-side base slot

    const unsigned short* Ag = A + (size_t)(m0 + 32 * w + lr) * K + sc * 8;
    const unsigned short* Bg = B + (size_t)(n0 + 32 * w + lr) * K + sc * 8;
    unsigned short* Al = As + (32 * w) * 64;
    unsigned short* Bl = Bs + (32 * w) * 64;

    for (int kb = 0; kb < K; kb += 64) {
        __syncthreads();
        #pragma unroll
        for (int p = 0; p < 4; ++p) {
            ld_lds16(Ag + (size_t)(8 * p) * K + kb, Al + (8 * p) * 64);
            ld_lds16(Bg + (size_t)(8 * p) * K + kb, Bl + (8 * p) * 64);
        }
        __syncthreads();
        FragU af[4][2], bf[4][2];
        #pragma unroll
        for (int i = 0; i < 4; ++i) {
            const int row = (wm + i * 16 + lm) * 64;
            af[i][0].u = *(const uint4*)&As[row + c0 * 8];
            af[i][1].u = *(const uint4*)&As[row + (c0 ^ 4) * 8];
        }
        #pragma unroll
        for (int j = 0; j < 4; ++j) {
            const int row = (wn + j * 16 + lm) * 64;
            bf[j][0].u = *(const uint4*)&Bs[row + c0 * 8];
            bf[j][1].u = *(const uint4*)&Bs[row + (c0 ^ 4) * 8];
        }
        #pragma unroll
        for (int i = 0; i < 4; ++i)
            #pragma unroll
            for (int j = 0; j < 4; ++j) {
                acc[i][j] = __builtin_amdgcn_mfma_f32_16x16x32_bf16(
                    af[i][0].b, bf[j][0].b, acc[i][j], 0, 0, 0);
                acc[i][j] = __builtin_amdgcn_mfma_f32_16x16x32_bf16(
                    af[i][1].b, bf[j][1].b, acc[i][j], 0, 0, 0);
            }
    }
}

// Fused QKV projection: A=xb [8192][2048], B=wb [3072][2048] (Wq|Wk|Wv rows).
// Grid 1536 blocks; bijective XCD swizzle (1536 = 8 x 192): each XCD gets a
// contiguous m-major chunk -> co-resident blocks share A-panels / cycle
// B-panels within its private L2 (T1).
__global__ __launch_bounds__(256)
void gemm_qkv(const unsigned short* __restrict__ A, const unsigned short* __restrict__ B,
              const float* __restrict__ bq, const float* __restrict__ bk,
              const float* __restrict__ bv,
              unsigned short* __restrict__ qb, unsigned short* __restrict__ kb,
              unsigned short* __restrict__ vb) {
    __shared__ __align__(16) unsigned short As[128 * 64];
    __shared__ __align__(16) unsigned short Bs[128 * 64];
    int id = blockIdx.y * 24 + blockIdx.x;
    id = (id & 7) * 192 + (id >> 3);
    const int m0 = (id / 24) * 128;
    const int n0 = (id % 24) * 128;
    floatx4 acc[4][4];
    #pragma unroll
    for (int i = 0; i < 4; ++i)
        #pragma unroll
        for (int j = 0; j < 4; ++j)
            acc[i][j] = (floatx4)(0.f);
    mfma_core<2048>(A, B, m0, n0, As, Bs, acc);

    const int t = threadIdx.x;
    const int w = t >> 6, l = t & 63;
    const int wm = (w >> 1) * 64, wn = (w & 1) * 64;
    const int lm = l & 15, lq = l >> 4;
    const int proj = n0 >> 10;
    unsigned short* Cb = proj == 0 ? qb : (proj == 1 ? kb : vb);
    const float* bias  = proj == 0 ? bq : (proj == 1 ? bk : bv);
    const int nd = n0 & 1023;
    #pragma unroll
    for (int j = 0; j < 4; ++j) {
        const int d = nd + wn + j * 16 + lm;
        const float bj = bias[d];
        #pragma unroll
        for (int i = 0; i < 4; ++i) {
            #pragma unroll
            for (int r = 0; r < 4; ++r) {
                const int row = m0 + wm + i * 16 + lq * 4 + r;
                Cb[(size_t)row * 1024 + d] = f2bf(acc[i][j][r] + bj);
            }
        }
    }
}

// Output projection: A=attn bf16 [8192][1024], B=wob [1024][1024]. fp32 out.
// 512 blocks = 8 XCDs x 64, m-major chunk per XCD.
__global__ __launch_bounds__(256)
void gemm_out(const unsigned short* __restrict__ A, const unsigned short* __restrict__ B,
              const float* __restrict__ bo, float* __restrict__ C) {
    __shared__ __align__(16) unsigned short As[128 * 64];
    __shared__ __align__(16) unsigned short Bs[128 * 64];
    int id = blockIdx.y * 8 + blockIdx.x;
    id = (id & 7) * 64 + (id >> 3);
    const int m0 = (id / 8) * 128;
    const int n0 = (id % 8) * 128;
    floatx4 acc[4][4];
    #pragma unroll
    for (int i = 0; i < 4; ++i)
        #pragma unroll
        for (int j = 0; j < 4; ++j)
            acc[i][j] = (floatx4)(0.f);
    mfma_core<1024>(A, B, m0, n0, As, Bs, acc);

    const int t = threadIdx.x;
    const int w = t >> 6, l = t & 63;
    const int wm = (w >> 1) * 64, wn = (w & 1) * 64;
    const int lm = l & 15, lq = l >> 4;
    #pragma unroll
    for (int j = 0; j < 4; ++j) {
        const int col = n0 + wn + j * 16 + lm;
        const float bj = bo[col];
        #pragma unroll
        for (int i = 0; i < 4; ++i) {
            #pragma unroll
            for (int r = 0; r < 4; ++r) {
                const int row = m0 + wm + i * 16 + lq * 4 + r;
                C[(size_t)row * EE + col] = acc[i][j][r] + bj;
            }
        }
    }
}

// ---- Stage 1 (MFMA): Sk[d][e] = sum_s sigma_k[s][d]*v[s][e], z[d]=colsum(sigma_k).
__global__ __launch_bounds__(256)
void seg_kv(const unsigned short* __restrict__ k, const unsigned short* __restrict__ v,
            float* __restrict__ Skv, float* __restrict__ zc) {
    __shared__ __align__(16) unsigned short KT[64 * 72];  // sigma_k^T [d][s]
    __shared__ __align__(16) unsigned short VT[64 * 72];  // v^T       [e][s]
    const int t = threadIdx.x;
    const int w = t >> 6, l = t & 63, quad = l >> 4, lm = l & 15;
    const size_t base = (size_t)blockIdx.x * 4096;

    #pragma unroll
    for (int i = 0; i < 2; ++i) {
        const int c  = t + i * 256;            // uint4 chunk
        const int sr = c >> 3, c0 = (c & 7) * 8;
        const uint4 pk = *(const uint4*)(k + base + c * 8);
        const uint4 pv = *(const uint4*)(v + base + c * 8);
        float4 f0, f1;
        unp8(pk, f0, f1);
        KT[(c0 + 0) * 72 + sr] = f2bf(elu1(f0.x));
        KT[(c0 + 1) * 72 + sr] = f2bf(elu1(f0.y));
        KT[(c0 + 2) * 72 + sr] = f2bf(elu1(f0.z));
        KT[(c0 + 3) * 72 + sr] = f2bf(elu1(f0.w));
        KT[(c0 + 4) * 72 + sr] = f2bf(elu1(f1.x));
        KT[(c0 + 5) * 72 + sr] = f2bf(elu1(f1.y));
        KT[(c0 + 6) * 72 + sr] = f2bf(elu1(f1.z));
        KT[(c0 + 7) * 72 + sr] = f2bf(elu1(f1.w));
        const unsigned short* pvs = (const unsigned short*)&pv;
        #pragma unroll
        for (int jj = 0; jj < 8; ++jj) VT[(c0 + jj) * 72 + sr] = pvs[jj];
    }
    __syncthreads();

    if (t < 64) {                                  // z[d] = rowsum of KT row d
        float ssum = 0.f;
        #pragma unroll
        for (int c2 = 0; c2 < 8; ++c2) {
            const uint4 p = *(const uint4*)&KT[t * 72 + c2 * 8];
            float4 a, b;
            unp8(p, a, b);
            ssum += a.x + a.y + a.z + a.w + b.x + b.y + b.z + b.w;
        }
        zc[(size_t)blockIdx.x * 64 + t] = ssum;
    }

    FragU ak0, ak1;
    ak0.u = *(const uint4*)&KT[(16 * w + lm) * 72 + quad * 8];
    ak1.u = *(const uint4*)&KT[(16 * w + lm) * 72 + 32 + quad * 8];
    floatx4 C4[4];
    #pragma unroll
    for (int j = 0; j < 4; ++j) C4[j] = (floatx4)(0.f);
    #pragma unroll
    for (int j = 0; j < 4; ++j) {
        FragU b0, b1;
        b0.u = *(const uint4*)&VT[(j * 16 + lm) * 72 + quad * 8];
        b1.u = *(const uint4*)&VT[(j * 16 + lm) * 72 + 32 + quad * 8];
        C4[j] = __builtin_amdgcn_mfma_f32_16x16x32_bf16(ak0.b, b0.b, C4[j], 0, 0, 0);
        C4[j] = __builtin_amdgcn_mfma_f32_16x16x32_bf16(ak1.b, b1.b, C4[j], 0, 0, 0);
    }
    const int d0 = 16 * w + quad * 4;
    #pragma unroll
    for (int j = 0; j < 4; ++j)
        #pragma unroll
        for (int r = 0; r < 4; ++r)
            Skv[base + (size_t)(d0 + r) * 64 + j * 16 + lm] = C4[j][r];
}

// ---- Stage 2: exclusive prefix over 16 segments per (b,h) chain.
// fp32 accumulation; bf16 output (seg_attn converts to bf16 anyway).
__global__ __launch_bounds__(256)
void prefix_mem(const float* __restrict__ Skv, unsigned short* __restrict__ Skvb,
                float* __restrict__ zc) {
    const int t  = threadIdx.x;
    const int bh = blockIdx.y;
    const size_t off = (size_t)bh * 16 * 4096 + blockIdx.x * 512 + t * 2;
    float2 acc = make_float2(0.f, 0.f);
    #pragma unroll
    for (int n = 0; n < 16; ++n) {
        const float2 tmp = *(const float2*)(Skv + off + (size_t)n * 4096);
        *(unsigned int*)(Skvb + off + (size_t)n * 4096) = pack2bf(acc.x, acc.y);
        acc.x += tmp.x; acc.y += tmp.y;
    }
    if (blockIdx.x == 0 && t < 64) {
        float* zp0 = zc + (size_t)bh * 16 * 64 + t;
        float za = 0.f;
        #pragma unroll
        for (int n = 0; n < 16; ++n) {
            float* zp = zp0 + n * 64;
            const float tmp = *zp;
            *zp = za;
            za += tmp;
        }
    }
}

// ---- Stage 3 (MFMA): per-segment attention. mem bf16 [d][e].
__global__ __launch_bounds__(256)
void seg_attn(const unsigned short* __restrict__ q, const unsigned short* __restrict__ k,
              const unsigned short* __restrict__ v, const unsigned short* __restrict__ memb,
              const float* __restrict__ zp, const float* __restrict__ beta,
              unsigned short* __restrict__ ab) {
    __shared__ __align__(16) unsigned short Pb[64 * 72];  // P bf16 [s][t]
    __shared__ __align__(16) unsigned short VT[64 * 72];  // v^T    [e][s]
    __shared__ __align__(16) unsigned short MT[64 * 72];  // mem^T  [e][d]
    __shared__ float rs[64];
    __shared__ float zr[64];
    const int t = threadIdx.x;
    const int w = t >> 6, l = t & 63, quad = l >> 4, lm = l & 15;
    const int seg = blockIdx.x;
    const int h   = (seg >> 4) & 15;
    const float gate = 1.f / (1.f + __expf(-10.f * beta[h]));
    const float omg  = 1.f - gate;
    const size_t base = (size_t)seg * 4096;

    // stage v^T
    #pragma unroll
    for (int i = 0; i < 2; ++i) {
        const int c  = t + i * 256;
        const int sr = c >> 3, c0 = (c & 7) * 8;
        const uint4 pv = *(const uint4*)(v + base + c * 8);
        const unsigned short* pvs = (const unsigned short*)&pv;
        #pragma unroll
        for (int jj = 0; jj < 8; ++jj) VT[(c0 + jj) * 72 + sr] = pvs[jj];
    }
    // stage mem^T (bf16 copy; source [d][e])
    #pragma unroll
    for (int i = 0; i < 2; ++i) {
        const int c = t + i * 256;
        const int d = c >> 3, e0 = (c & 7) * 8;
        const uint4 pm = *(const uint4*)(memb + base + c * 8);
        const unsigned short* pms = (const unsigned short*)&pm;
        #pragma unroll
        for (int jj = 0; jj < 8; ++jj) MT[(e0 + jj) * 72 + d] = pms[jj];
    }
    // rs[s] = rowsum(sigma_q): quarter-row per thread + shfl reduce
    {
        const int s = t >> 2, dq = (t & 3) * 16;
        const uint4 a0 = *(const uint4*)(q + base + s * 64 + dq);
        const uint4 a1 = *(const uint4*)(q + base + s * 64 + dq + 8);
        float4 f0, f1, f2, f3;
        unp8(a0, f0, f1); unp8(a1, f2, f3);
        float p = elu1(f0.x) + elu1(f0.y) + elu1(f0.z) + elu1(f0.w)
                + elu1(f1.x) + elu1(f1.y) + elu1(f1.z) + elu1(f1.w)
                + elu1(f2.x) + elu1(f2.y) + elu1(f2.z) + elu1(f2.w)
                + elu1(f3.x) + elu1(f3.y) + elu1(f3.z) + elu1(f3.w);
        p += __shfl_xor(p, 1, 64);
        p += __shfl_xor(p, 2, 64);
        if ((t & 3) == 0) rs[s] = p;
    }
    if (t < 64) zr[t] = zp[(size_t)seg * 64 + t];
    __syncthreads();

    // ---- scores: wave w computes rows [16w,16w+16) x all 64 cols
    const unsigned short* qrow = q + base + (size_t)(16 * w + lm) * 64;
    FragU aq0, aq1;
    aq0.u = *(const uint4*)(qrow + quad * 8);
    aq1.u = *(const uint4*)(qrow + 32 + quad * 8);
    floatx4 S[4];
    #pragma unroll
    for (int j = 0; j < 4; ++j) S[j] = (floatx4)(0.f);
    #pragma unroll
    for (int j = 0; j < 4; ++j) {
        const unsigned short* krow = k + base + (size_t)(j * 16 + lm) * 64;
        FragU b0, b1;
        b0.u = *(const uint4*)(krow + quad * 8);
        b1.u = *(const uint4*)(krow + 32 + quad * 8);
        S[j] = __builtin_amdgcn_mfma_f32_16x16x32_bf16(aq0.b, b0.b, S[j], 0, 0, 0);
        S[j] = __builtin_amdgcn_mfma_f32_16x16x32_bf16(aq1.b, b1.b, S[j], 0, 0, 0);
    }
    // ---- causal softmax in C-layout registers; write P bf16 to LDS
    const int srow0 = 16 * w + quad * 4;
    #pragma unroll
    for (int r = 0; r < 4; ++r) {
        const int s_g = srow0 + r;
        float m = -3.0e38f;
        #pragma unroll
        for (int j = 0; j < 4; ++j) {
            const int t_g = j * 16 + lm;
            const float val = (t_g <= s_g) ? S[j][r] * 0.125f : -3.0e38f;
            S[j][r] = val;
            m = fmaxf(m, val);
        }
        m = fmaxf(m, __shfl_xor(m, 1, 64));
        m = fmaxf(m, __shfl_xor(m, 2, 64));
        m = fmaxf(m, __shfl_xor(m, 4, 64));
        m = fmaxf(m, __shfl_xor(m, 8, 64));
        float ss = 0.f;
        #pragma unroll
        for (int j = 0; j < 4; ++j) {
            const int t_g = j * 16 + lm;
            const float e = (t_g <= s_g) ? __expf(S[j][r] - m) : 0.f;
            S[j][r] = e;
            ss += e;
        }
        ss += __shfl_xor(ss, 1, 64);
        ss += __shfl_xor(ss, 2, 64);
        ss += __shfl_xor(ss, 4, 64);
        ss += __shfl_xor(ss, 8, 64);
        const float inv = 1.f / ss;
        #pragma unroll
        for (int j = 0; j < 4; ++j)
            Pb[s_g * 72 + j * 16 + lm] = f2bf(S[j][r] * inv);
    }
    __syncthreads();

    // ---- A_dot = P@V and A_mem = sigma_q@mem (both C-layout accumulators)
    FragU ap0, ap1, as0, as1;
    ap0.u = *(const uint4*)&Pb[(16 * w + lm) * 72 + quad * 8];
    ap1.u = *(const uint4*)&Pb[(16 * w + lm) * 72 + 32 + quad * 8];
    {
        float4 f0, f1, f2, f3;
        unp8(aq0.u, f0, f1);
        unp8(aq1.u, f2, f3);
        f0.x = elu1(f0.x); f0.y = elu1(f0.y); f0.z = elu1(f0.z); f0.w = elu1(f0.w);
        f1.x = elu1(f1.x); f1.y = elu1(f1.y); f1.z = elu1(f1.z); f1.w = elu1(f1.w);
        f2.x = elu1(f2.x); f2.y = elu1(f2.y); f2.z = elu1(f2.z); f2.w = elu1(f2.w);
        f3.x = elu1(f3.x); f3.y = elu1(f3.y); f3.z = elu1(f3.z); f3.w = elu1(f3.w);
        as0.u = pack8bf(f0, f1);
        as1.u = pack8bf(f2, f3);
    }
    floatx4 AD[4], AM[4];
    #pragma unroll
    for (int j = 0; j < 4; ++j) { AD[j] = (floatx4)(0.f); AM[j] = (floatx4)(0.f); }
    #pragma unroll
    for (int j = 0; j < 4; ++j) {
        FragU bv0, bv1, bm0, bm1;
        bv0.u = *(const uint4*)&VT[(j * 16 + lm) * 72 + quad * 8];
        bv1.u = *(const uint4*)&VT[(j * 16 + lm) * 72 + 32 + quad * 8];
        bm0.u = *(const uint4*)&MT[(j * 16 + lm) * 72 + quad * 8];
        bm1.u = *(const uint4*)&MT[(j * 16 + lm) * 72 + 32 + quad * 8];
        AD[j] = __builtin_amdgcn_mfma_f32_16x16x32_bf16(ap0.b, bv0.b, AD[j], 0, 0, 0);
        AD[j] = __builtin_amdgcn_mfma_f32_16x16x32_bf16(ap1.b, bv1.b, AD[j], 0, 0, 0);
        AM[j] = __builtin_amdgcn_mfma_f32_16x16x32_bf16(as0.b, bm0.b, AM[j], 0, 0, 0);
        AM[j] = __builtin_amdgcn_mfma_f32_16x16x32_bf16(as1.b, bm1.b, AM[j], 0, 0, 0);
    }
    // ---- combine + store attn bf16
    #pragma unroll
    for (int j = 0; j < 4; ++j) {
        const int d = j * 16 + lm;
        const float zd = zr[d];
        #pragma unroll
        for (int r = 0; r < 4; ++r) {
            const int s_g = srow0 + r;
            const float den = rs[s_g] * zd + 1e-6f;
            const float o = gate * (AM[j][r] / den) + omg * AD[j][r];
            ab[base + (size_t)s_g * 64 + d] = f2bf(o);
        }
    }
}

extern "C" void kernel_launch(void* const* d_in, const int* in_sizes, int n_in,
                              void* d_out, int out_size, void* d_ws, size_t ws_size,
                              hipStream_t stream) {
    const float* x    = (const float*)d_in[0];
    const float* Wq   = (const float*)d_in[1];
    const float* bq   = (const float*)d_in[2];
    const float* Wk   = (const float*)d_in[3];
    const float* bk   = (const float*)d_in[4];
    const float* Wv   = (const float*)d_in[5];
    const float* bv   = (const float*)d_in[6];
    const float* Wo   = (const float*)d_in[7];
    const float* bo   = (const float*)d_in[8];
    const float* beta = (const float*)d_in[9];
    float* out = (float*)d_out;

    unsigned char* wsb = (unsigned char*)d_ws;
    unsigned short* xb  = (unsigned short*)(wsb);                       // 32 MB
    unsigned short* wb  = (unsigned short*)(wsb + (32ull << 20));       // 12 MB  [3072][2048]
    unsigned short* wob = (unsigned short*)(wsb + (44ull << 20));       // 2 MB   [1024][1024]
    unsigned short* qb  = (unsigned short*)(wsb + (46ull << 20));       // 16 MB
    unsigned short* kb  = (unsigned short*)(wsb + (62ull << 20));       // 16 MB
    unsigned short* vb  = (unsigned short*)(wsb + (78ull << 20));       // 16 MB
    float* Skv = (float*)(wsb + (94ull << 20));                         // 32 MB
    float* zc  = (float*)(wsb + (126ull << 20));                        // 0.5 MB
    unsigned short* ab   = xb;                                          // first 16 MB of xb (dead after gemm_qkv)
    unsigned short* Skvb = (unsigned short*)(wsb + (16ull << 20));      // second 16 MB of xb (dead after gemm_qkv)

    cvt_all<<<11776, 256, 0, stream>>>(x, Wq, Wk, Wv, Wo, xb, wb, wob);

    gemm_qkv<<<dim3(24, 64), 256, 0, stream>>>(xb, wb, bq, bk, bv, qb, kb, vb);
    seg_kv<<<2048, 256, 0, stream>>>(kb, vb, Skv, zc);
    prefix_mem<<<dim3(8, 128), 256, 0, stream>>>(Skv, Skvb, zc);
    seg_attn<<<2048, 256, 0, stream>>>(qb, kb, vb, Skvb, zc, beta, ab);
    gemm_out<<<dim3(8, 64), 256, 0, stream>>>(ab, wob, bo, out);
}